// Round 2
// baseline (208.001 us; speedup 1.0000x reference)
//
#include <hip/hip_runtime.h>

#define HP 192
#define WP 192
#define NPIX (HP * WP)   // 36864
#define SG 24

// ---------------- Kernel 1: QKV projection (unchanged) ------------------------
__global__ __launch_bounds__(256) void qkv_kernel(
    const float* __restrict__ x,
    const float* __restrict__ w_qk,
    const float* __restrict__ w_v,
    float* __restrict__ qb, float* __restrict__ kb, float* __restrict__ vb) {
  const int jb = blockIdx.y;  // 0..5
  const int pix = blockIdx.x * 256 + threadIdx.x;
  float xv[64];
#pragma unroll
  for (int c = 0; c < 64; ++c) xv[c] = x[c * NPIX + pix];
  float acc[32];
#pragma unroll
  for (int j = 0; j < 32; ++j) acc[j] = 0.f;
  const int j0 = jb * 32;
  if (jb < 4) {
#pragma unroll
    for (int c = 0; c < 64; ++c) {
      const float* wr = w_qk + c * 128 + j0;
      const float xc = xv[c];
#pragma unroll
      for (int j = 0; j < 32; ++j) acc[j] = fmaf(xc, wr[j], acc[j]);
    }
  } else {
#pragma unroll
    for (int c = 0; c < 64; ++c) {
      const float* wr = w_v + c * 64 + (j0 - 128);
      const float xc = xv[c];
#pragma unroll
      for (int j = 0; j < 32; ++j) acc[j] = fmaf(xc, wr[j], acc[j]);
    }
  }
  float* dst;
  float mul = 1.0f;
  if (jb < 2) {
    dst = qb + (size_t)pix * 64 + j0;
    mul = 0.25f;  // hd^-0.5, hd=16
  } else if (jb < 4) {
    dst = kb + (size_t)pix * 64 + (j0 - 64);
  } else {
    dst = vb + (size_t)pix * 64 + (j0 - 128);
  }
#pragma unroll
  for (int j = 0; j < 32; ++j) dst[j] = acc[j] * mul;
}

// ---------------- Kernel 2: attention, K tile staged in LDS -------------------
// Block = 8x8 pixel tile, 256 threads = 64 px x 4 heads.
// smK: [196 locations][64 floats], float4-swizzled: logical quad d4 of location
// loc stored at phys quad d4 ^ (loc & 7)  -> location stride (256 B) no longer
// aliases bank 0; reads spread over 8 bank-groups.
// smpi: [196][12(pad)] floats, quad-broadcast reads (4 heads share address).
__global__ __launch_bounds__(256) void attn_kernel(
    const float* __restrict__ qb, const float* __restrict__ kb,
    const float* __restrict__ vb, const float* __restrict__ sims,
    float* __restrict__ pre) {
  __shared__ __align__(16) float smK[196 * 64];
  __shared__ __align__(16) float smpi[196 * 12];
  const int tile = blockIdx.x;
  const int th = tile / 24, tw = tile % 24;
  const int rowBase = th * 8 - 3, colBase = tw * 8 - 3;
  const int tid = threadIdx.x;

  // ---- stage K tile (coalesced global float4 -> swizzled LDS) ----
  for (int i = tid; i < 196 * 16; i += 256) {
    const int loc = i >> 4, d4 = i & 15;
    const int rl = loc / 14, cl = loc - rl * 14;
    const int r = rowBase + rl, c = colBase + cl;
    float4 val = make_float4(0.f, 0.f, 0.f, 0.f);
    if (r >= 0 && r < HP && c >= 0 && c < WP)
      val = *(const float4*)(kb + ((size_t)(r * WP + c)) * 64 + (d4 << 2));
    *(float4*)(smK + (loc << 6) + ((d4 ^ (loc & 7)) << 2)) = val;
  }
  // ---- stage pi table: 196 locations x 9 block-uniform labels ----
  for (int i = tid; i < 196 * 9; i += 256) {
    const int loc = i / 9, s = i - loc * 9;
    const int rl = loc / 14, cl = loc - rl * 14;
    const int r = rowBase + rl, c = colBase + cl;
    const int dh = s / 3, dw = s - dh * 3;
    const int shi = th + dh - 1, swj = tw + dw - 1;
    float val = 0.f;
    if (shi >= 0 && shi < SG && swj >= 0 && swj < SG && r >= 0 && r < HP &&
        c >= 0 && c < WP)
      val = sims[((size_t)(r * WP + c)) * (SG * SG) + shi * SG + swj];
    smpi[loc * 12 + s] = val;
  }
  __syncthreads();

  const int head = tid & 3;
  const int pl = tid >> 2;
  const int py = pl >> 3, px = pl & 7;
  const int h = th * 8 + py, w = tw * 8 + px;
  const int pix = h * WP + w;
  int hs = h - 3;
  hs = hs < 0 ? 0 : (hs > HP - 7 ? HP - 7 : hs);
  int wsb = w - 3;
  wsb = wsb < 0 ? 0 : (wsb > WP - 7 ? WP - 7 : wsb);
  const int rl0 = hs - rowBase;   // 0..7
  const int cl0 = wsb - colBase;  // 0..7

  const float4* qp = (const float4*)(qb + (size_t)pix * 64 + head * 16);
  const float4 q0 = qp[0], q1 = qp[1], q2 = qp[2], q3 = qp[3];
  const int h16 = head << 2;  // head quad index base (4h)

  // ---- logits from LDS K ----
  float a[49];
  float m = -1e30f;
#pragma unroll
  for (int kh = 0; kh < 7; ++kh) {
    const int rbase = (rl0 + kh) * 14 + cl0;
#pragma unroll
    for (int kw = 0; kw < 7; ++kw) {
      const int loc = rbase + kw;
      // phys quad for logical j: (4h+j)^(loc&7); j-part XORs bits 2-3 of idx
      const int b0 = (loc << 6) + ((((h16) ^ (loc & 4)) | (loc & 3)) << 2);
      const float4 k0 = *(const float4*)(smK + (b0 ^ 0));
      const float4 k1 = *(const float4*)(smK + (b0 ^ 4));
      const float4 k2 = *(const float4*)(smK + (b0 ^ 8));
      const float4 k3 = *(const float4*)(smK + (b0 ^ 12));
      float t = q0.x * k0.x + q0.y * k0.y + q0.z * k0.z + q0.w * k0.w;
      t += q1.x * k1.x + q1.y * k1.y + q1.z * k1.z + q1.w * k1.w;
      t += q2.x * k2.x + q2.y * k2.y + q2.z * k2.z + q2.w * k2.w;
      t += q3.x * k3.x + q3.y * k3.y + q3.z * k3.z + q3.w * k3.w;
      a[kh * 7 + kw] = t;
      m = fmaxf(m, t);
    }
  }

  // ---- fused exp + superpixel denominators (unnormalized) ----
  float D9[9];
#pragma unroll
  for (int s = 0; s < 9; ++s) D9[s] = 0.f;
  float S = 0.f;
#pragma unroll
  for (int kh = 0; kh < 7; ++kh) {
    const int rbase = (rl0 + kh) * 14 + cl0;
#pragma unroll
    for (int kw = 0; kw < 7; ++kw) {
      const int loc = rbase + kw;
      const float e = __expf(a[kh * 7 + kw] - m);
      a[kh * 7 + kw] = e;
      S += e;
      const float* pp = smpi + loc * 12;
      const float4 p0 = *(const float4*)pp;
      const float4 p1 = *(const float4*)(pp + 4);
      const float p8 = pp[8];
      D9[0] = fmaf(e, p0.x, D9[0]);
      D9[1] = fmaf(e, p0.y, D9[1]);
      D9[2] = fmaf(e, p0.z, D9[2]);
      D9[3] = fmaf(e, p0.w, D9[3]);
      D9[4] = fmaf(e, p1.x, D9[4]);
      D9[5] = fmaf(e, p1.y, D9[5]);
      D9[6] = fmaf(e, p1.z, D9[6]);
      D9[7] = fmaf(e, p1.w, D9[7]);
      D9[8] = fmaf(e, p8, D9[8]);
    }
  }

  // ---- coef_s = ws[s] / (D[s] + 1e-10*S)  (invS folded in) ----
  float coef[9];
  {
    const int rl = h - rowBase, cl = w - colBase;
    const float* pp = smpi + (rl * 14 + cl) * 12;
    const float4 p0 = *(const float4*)pp;
    const float4 p1 = *(const float4*)(pp + 4);
    const float p8 = pp[8];
    const float epsS = 1e-10f * S;
    coef[0] = p0.x / (D9[0] + epsS);
    coef[1] = p0.y / (D9[1] + epsS);
    coef[2] = p0.z / (D9[2] + epsS);
    coef[3] = p0.w / (D9[3] + epsS);
    coef[4] = p1.x / (D9[4] + epsS);
    coef[5] = p1.y / (D9[5] + epsS);
    coef[6] = p1.z / (D9[6] + epsS);
    coef[7] = p1.w / (D9[7] + epsS);
    coef[8] = p8 / (D9[8] + epsS);
  }

  // ---- pass 2: a2 = e * (coef . pi);  out += a2 * v (global, cached) ----
  float4 o0 = make_float4(0.f, 0.f, 0.f, 0.f);
  float4 o1 = make_float4(0.f, 0.f, 0.f, 0.f);
  float4 o2 = make_float4(0.f, 0.f, 0.f, 0.f);
  float4 o3 = make_float4(0.f, 0.f, 0.f, 0.f);
#pragma unroll
  for (int kh = 0; kh < 7; ++kh) {
    const int hn = hs + kh;
    const int rbase = (rl0 + kh) * 14 + cl0;
#pragma unroll
    for (int kw = 0; kw < 7; ++kw) {
      const int wn = wsb + kw;
      const int loc = rbase + kw;
      const float* pp = smpi + loc * 12;
      const float4 p0 = *(const float4*)pp;
      const float4 p1 = *(const float4*)(pp + 4);
      const float p8 = pp[8];
      float t = coef[0] * p0.x + coef[1] * p0.y + coef[2] * p0.z +
                coef[3] * p0.w + coef[4] * p1.x + coef[5] * p1.y +
                coef[6] * p1.z + coef[7] * p1.w + coef[8] * p8;
      const float a2 = a[kh * 7 + kw] * t;
      const float4* vp =
          (const float4*)(vb + (size_t)(hn * WP + wn) * 64 + head * 16);
      const float4 v0 = vp[0], v1 = vp[1], v2 = vp[2], v3 = vp[3];
      o0.x = fmaf(a2, v0.x, o0.x);
      o0.y = fmaf(a2, v0.y, o0.y);
      o0.z = fmaf(a2, v0.z, o0.z);
      o0.w = fmaf(a2, v0.w, o0.w);
      o1.x = fmaf(a2, v1.x, o1.x);
      o1.y = fmaf(a2, v1.y, o1.y);
      o1.z = fmaf(a2, v1.z, o1.z);
      o1.w = fmaf(a2, v1.w, o1.w);
      o2.x = fmaf(a2, v2.x, o2.x);
      o2.y = fmaf(a2, v2.y, o2.y);
      o2.z = fmaf(a2, v2.z, o2.z);
      o2.w = fmaf(a2, v2.w, o2.w);
      o3.x = fmaf(a2, v3.x, o3.x);
      o3.y = fmaf(a2, v3.y, o3.y);
      o3.z = fmaf(a2, v3.z, o3.z);
      o3.w = fmaf(a2, v3.w, o3.w);
    }
  }
  float4* op = (float4*)(pre + (size_t)pix * 64 + head * 16);
  op[0] = o0;
  op[1] = o1;
  op[2] = o2;
  op[3] = o3;
}

// ---------------- Kernel 3: output projection (unchanged) ---------------------
__global__ __launch_bounds__(256) void proj_kernel(
    const float* __restrict__ pre, const float* __restrict__ w_proj,
    float* __restrict__ out) {
  const int jb = blockIdx.y;  // 0..1
  const int pix = blockIdx.x * 256 + threadIdx.x;
  float xv[64];
  const float4* pp = (const float4*)(pre + (size_t)pix * 64);
#pragma unroll
  for (int i = 0; i < 16; ++i) {
    const float4 t = pp[i];
    xv[i * 4 + 0] = t.x;
    xv[i * 4 + 1] = t.y;
    xv[i * 4 + 2] = t.z;
    xv[i * 4 + 3] = t.w;
  }
  float acc[32];
#pragma unroll
  for (int j = 0; j < 32; ++j) acc[j] = 0.f;
  const int j0 = jb * 32;
#pragma unroll
  for (int c = 0; c < 64; ++c) {
    const float* wr = w_proj + c * 64 + j0;
    const float xc = xv[c];
#pragma unroll
    for (int j = 0; j < 32; ++j) acc[j] = fmaf(xc, wr[j], acc[j]);
  }
#pragma unroll
  for (int j = 0; j < 32; ++j) out[(size_t)(j0 + j) * NPIX + pix] = acc[j];
}

extern "C" void kernel_launch(void* const* d_in, const int* in_sizes, int n_in,
                              void* d_out, int out_size, void* d_ws,
                              size_t ws_size, hipStream_t stream) {
  const float* x = (const float*)d_in[0];
  const float* sims = (const float*)d_in[1];
  const float* w_qk = (const float*)d_in[2];
  const float* w_v = (const float*)d_in[3];
  const float* w_proj = (const float*)d_in[4];
  float* out = (float*)d_out;

  float* qb = (float*)d_ws;
  float* kb = qb + (size_t)NPIX * 64;
  float* vb = kb + (size_t)NPIX * 64;
  float* pre = vb + (size_t)NPIX * 64;

  qkv_kernel<<<dim3(144, 6), 256, 0, stream>>>(x, w_qk, w_v, qb, kb, vb);
  attn_kernel<<<dim3(576), 256, 0, stream>>>(qb, kb, vb, sims, pre);
  proj_kernel<<<dim3(144, 2), 256, 0, stream>>>(pre, w_proj, out);
}